// Round 3
// baseline (3830.284 us; speedup 1.0000x reference)
//
#include <hip/hip_runtime.h>

typedef unsigned short u16;
typedef short v8s   __attribute__((ext_vector_type(8)));
typedef float f32x4 __attribute__((ext_vector_type(4)));
typedef float f32x2 __attribute__((ext_vector_type(2)));

#define H_ 256
#define B_ 8192
#define NSTEP 31
#define NTHREADS 1024
#define NBLOCKS 256
#define AROW 264   // 256 + 8 bf16 pad -> 528B row stride

#define MFMA16(a,b,c) __builtin_amdgcn_mfma_f32_16x16x32_bf16(a,b,c,0,0,0)

#define DPP_QP_XOR1 0xB1
#define DPP_QP_XOR2 0x4E
#define DPP_ROR4    0x124
#define DPP_ROR8    0x128

template<int CTRL>
__device__ __forceinline__ float dpp_add(float v){
  return v + __int_as_float(
      __builtin_amdgcn_update_dpp(0, __float_as_int(v), CTRL, 0xF, 0xF, true));
}

__device__ __forceinline__ u16 f2bf_rne(float f){
  unsigned u = __float_as_uint(f);
  u += 0x7fffu + ((u >> 16) & 1u);
  return (u16)(u >> 16);
}
__device__ __forceinline__ u16 f2bf_trunc(float f){
  return (u16)(__float_as_uint(f) >> 16);
}

// ---- workspace layout (u16 units) ----
#define WS_W0   0        // [q][n][j] 4*256*8 = 8192 (K-padded to 32; k==6 row = b0)
#define WS_W1   8192     // [n][k]   256*256 = 65536 (Wh[0] transposed)
#define WS_W23  73728    // [l][q][col][kc][j] 2*4*256*64 = 131072 (frag-contiguous per lane)
#define WS_WO   204800   // [kc][q][nn][j] 8*4*4*8 = 1024
#define WS_TOT  205824

__global__ void prep_kernel(const float* __restrict__ W0,
                            const float* __restrict__ b0,
                            const float* __restrict__ Wh,
                            const float* __restrict__ Wout,
                            u16* __restrict__ ws){
  int i = blockIdx.x * 256 + threadIdx.x;
  if (i < 8192){
    int q = i >> 11, n = (i >> 3) & 255, j = i & 7;
    int k = q*8 + j;
    float v = (k < 6) ? W0[k*H_ + n] : ((k == 6) ? b0[n] : 0.f);
    ws[i] = f2bf_rne(v);
  } else if (i < 73728){
    int r = i - 8192;
    int n = r >> 8, k = r & 255;
    ws[i] = f2bf_rne(Wh[k*H_ + n]);
  } else if (i < 204800){
    int r = i - 73728;
    int j = r & 7, kc = (r >> 3) & 7, col = (r >> 6) & 255;
    int q = (r >> 14) & 3, l = (r >> 16) & 1;
    int k = kc*32 + q*8 + j;
    ws[i] = f2bf_rne(Wh[(1 + l)*H_*H_ + k*H_ + col]);
  } else if (i < WS_TOT){
    int r = i - 204800;
    int kc = r >> 7, q = (r >> 5) & 3, nn = (r >> 3) & 3, j = r & 7;
    int k = kc*32 + q*8 + j;
    ws[i] = f2bf_rne(nn < 3 ? Wout[k*3 + nn] : 0.f);
  }
}

// ---- LDS layout (bytes) ----
#define PWF 20              // partials row stride in f32 (80B, 16B-aligned, odd 16B-chunk count)
#define OFF_A      0        // 16896
#define OFF_W1     16896    // 135168
#define OFF_WOUT   152064   // 2048
#define OFF_PART   154112   // 32*80 = 2560
#define OFF_NET    156672   // 512
#define OFF_YCUR   157184
#define OFF_YSUM   157696
#define OFF_YSTG   158208
#define OFF_P      158720
#define OFF_DTS    159232   // 128
#define LDS_TOTAL  159360   // <= 163840

__global__ __launch_bounds__(NTHREADS, 4)
void pinode_kernel(const float* __restrict__ y0g, const float* __restrict__ t_span,
                   const float* __restrict__ params, const float* __restrict__ bhg,
                   const float* __restrict__ ln_gg, const float* __restrict__ ln_bg,
                   const float* __restrict__ boutg, const float* __restrict__ gatep,
                   const u16* __restrict__ ws, float* __restrict__ out)
{
  extern __shared__ char smem[];
  u16*   A     = (u16*)(smem + OFF_A);
  u16*   W1    = (u16*)(smem + OFF_W1);
  u16*   WO    = (u16*)(smem + OFF_WOUT);
  float* partf = (float*)(smem + OFF_PART);
  float* net   = (float*)(smem + OFF_NET);
  float* ycur  = (float*)(smem + OFF_YCUR);
  float* ysum  = (float*)(smem + OFF_YSUM);
  float* ystg  = (float*)(smem + OFF_YSTG);
  float* pL    = (float*)(smem + OFF_P);
  float* dts   = (float*)(smem + OFF_DTS);

  const int tid  = threadIdx.x;
  const int wave = tid >> 6;
  const int lane = tid & 63;
  const int q    = lane >> 4;
  const int c15  = lane & 15;
  const int mg   = wave & 1;        // row-group (16 rows)
  const int cg   = wave >> 1;       // col-group (32 cols)
  const int colbase = cg * 32;
  const int rowbase = mg * 16;
  const int s0 = blockIdx.x * 32;

  // ---- startup staging ----
  for (int idx = tid; idx < 8192; idx += NTHREADS){
    int n = idx >> 5, ch = idx & 31;
    *(v8s*)(W1 + n*AROW + ch*8) = *(const v8s*)(ws + WS_W1 + n*256 + ch*8);
  }
  if (tid < 128)
    *(v8s*)(WO + tid*8) = *(const v8s*)(ws + WS_WO + tid*8);
  if (tid < 96){
    int s = tid & 31, c = tid >> 5;
    float y = y0g[(s0+s)*3 + c];
    ycur[s*4+c] = y; ystg[s*4+c] = y;
    pL[s*4+c]   = params[(s0+s)*3 + c];
    out[(s0+s)*3 + c] = y;
  }
  if (tid < NSTEP) dts[tid] = t_span[tid+1] - t_span[tid];

  // W0 fragments (registers, loaded once)
  v8s w0f[2];
#pragma unroll
  for (int nt = 0; nt < 2; ++nt)
    w0f[nt] = *(const v8s*)(ws + WS_W0 + (q*256 + colbase + nt*16 + c15)*8);

  // per-lane base for W2/W3 fragment stream (L2-resident)
  const u16* gwb = ws + WS_W23 + (q*256 + colbase + c15)*64;

  float lng[4][2], lnb[4][2], bia[3][2];
#pragma unroll
  for (int l = 0; l < 4; ++l)
#pragma unroll
    for (int nt = 0; nt < 2; ++nt){
      int col = colbase + nt*16 + c15;
      lng[l][nt] = ln_gg[l*H_ + col];
      lnb[l][nt] = ln_bg[l*H_ + col];
      if (l >= 1) bia[l-1][nt] = bhg[(l-1)*H_ + col];
    }
  const float gate = gatep[0];
  const float bo0 = boutg[0], bo1 = boutg[1], bo2 = boutg[2];
  const f32x4 fzero = {0.f, 0.f, 0.f, 0.f};

  const u16* pa   = A + (rowbase + c15)*AROW + q*8;          // A-frag base (16 rows)
  const u16* pw   = W1 + (colbase + c15)*AROW + q*8;         // W1 frag base
  u16*       pstA = A + (rowbase + q*4)*AROW + colbase + c15;

  __syncthreads();

  // initial A rows: [y(3), p(3), 1.0, 0] + zero cols 8..31 (guard vs garbage NaN)
  if (tid < 32){
    int s = tid;
    union { u16 h[8]; v8s v; } pk;
    pk.h[0]=f2bf_rne(ystg[s*4+0]); pk.h[1]=f2bf_rne(ystg[s*4+1]); pk.h[2]=f2bf_rne(ystg[s*4+2]);
    pk.h[3]=f2bf_rne(pL[s*4+0]);   pk.h[4]=f2bf_rne(pL[s*4+1]);   pk.h[5]=f2bf_rne(pL[s*4+2]);
    pk.h[6]=0x3F80; pk.h[7]=0;
    *(v8s*)(A + s*AROW) = pk.v;
    v8s z = {0,0,0,0,0,0,0,0};
    *(v8s*)(A + s*AROW + 8)  = z;
    *(v8s*)(A + s*AROW + 16) = z;
    *(v8s*)(A + s*AROW + 24) = z;
  }

  // prefetch W2 fragments
  v8s wN[2][8];
#pragma unroll
  for (int nt = 0; nt < 2; ++nt)
#pragma unroll
    for (int kc = 0; kc < 8; ++kc)
      wN[nt][kc] = *(const v8s*)(gwb + nt*1024 + kc*8);

  __syncthreads();

  // LayerNorm + SiLU + bf16 store to A — 2 barriers
  auto ln_silu = [&](f32x4 (&acc)[2], int li){
    float rs[4], rq[4];
#pragma unroll
    for (int r = 0; r < 4; ++r){
      float a0 = acc[0][r], a1 = acc[1][r];
      rs[r] = a0 + a1;
      rq[r] = a0*a0 + a1*a1;
    }
#pragma unroll
    for (int r = 0; r < 4; ++r){
      float s = rs[r], qq = rq[r];
      s = dpp_add<DPP_QP_XOR1>(s);  qq = dpp_add<DPP_QP_XOR1>(qq);
      s = dpp_add<DPP_QP_XOR2>(s);  qq = dpp_add<DPP_QP_XOR2>(qq);
      s = dpp_add<DPP_ROR4>(s);     qq = dpp_add<DPP_ROR4>(qq);
      s = dpp_add<DPP_ROR8>(s);     qq = dpp_add<DPP_ROR8>(qq);
      rs[r] = s; rq[r] = qq;
    }
    if (c15 == 0){
#pragma unroll
      for (int r = 0; r < 4; ++r){
        f32x2 v; v.x = rs[r]; v.y = rq[r];
        *(f32x2*)(partf + (rowbase + q*4 + r)*PWF + cg*2) = v;
      }
    }
    __syncthreads();
    // redundant per-wave stats: lane (&31) owns one row
    int r32 = lane & 31;
    const f32x4* pp = (const f32x4*)(partf + r32*PWF);
    f32x4 p0 = pp[0], p1 = pp[1], p2 = pp[2], p3 = pp[3];
    float S = ((p0[0]+p0[2])+(p1[0]+p1[2]))+((p2[0]+p2[2])+(p3[0]+p3[2]));
    float Q = ((p0[1]+p0[3])+(p1[1]+p1[3]))+((p2[1]+p2[3])+(p3[1]+p3[3]));
    float mean = S * (1.f/256.f);
    float var  = Q * (1.f/256.f) - mean*mean;
    float rstd = rsqrtf(var + 1e-5f);
    float nmr  = -mean * rstd;
#pragma unroll
    for (int r = 0; r < 4; ++r){
      int row = rowbase + q*4 + r;
      float sr = __int_as_float(__builtin_amdgcn_ds_bpermute(row << 2, __float_as_int(rstd)));
      float sb = __int_as_float(__builtin_amdgcn_ds_bpermute(row << 2, __float_as_int(nmr)));
#pragma unroll
      for (int nt = 0; nt < 2; ++nt){
        float t  = acc[nt][r] * sr + sb;
        float v  = t * lng[li][nt] + lnb[li][nt];
        float e  = __builtin_amdgcn_exp2f(v * -1.44269504f);
        float sv = v * __builtin_amdgcn_rcpf(1.f + e);
        pstA[r*AROW + nt*16] = f2bf_trunc(sv);
      }
    }
    __syncthreads();
  };

#pragma unroll 1
  for (int step = 0; step < NSTEP; ++step){
    float dt = dts[step];
#pragma unroll 1
    for (int stage = 0; stage < 4; ++stage){
      f32x4 acc[2];

      // ---- layer 0 ----
      acc[0] = fzero; acc[1] = fzero;
      {
        v8s a = *(const v8s*)(pa);
        acc[0] = MFMA16(a, w0f[0], acc[0]);
        acc[1] = MFMA16(a, w0f[1], acc[1]);
      }
      ln_silu(acc, 0);

      // ---- layer 1: W1 from LDS ----
      acc[0] = fzero; acc[1] = fzero;
#pragma unroll
      for (int kc = 0; kc < 8; ++kc){
        v8s a  = *(const v8s*)(pa + kc*32);
        v8s b0_ = *(const v8s*)(pw + kc*32);
        v8s b1_ = *(const v8s*)(pw + 16*AROW + kc*32);
        acc[0] = MFMA16(a, b0_, acc[0]);
        acc[1] = MFMA16(a, b1_, acc[1]);
      }
#pragma unroll
      for (int nt = 0; nt < 2; ++nt)
#pragma unroll
        for (int r = 0; r < 4; ++r) acc[nt][r] += bia[0][nt];
      ln_silu(acc, 1);

      // ---- layer 2: wN = W2 ----
      acc[0] = fzero; acc[1] = fzero;
#pragma unroll
      for (int kc = 0; kc < 8; ++kc){
        v8s a = *(const v8s*)(pa + kc*32);
        acc[0] = MFMA16(a, wN[0][kc], acc[0]);
        acc[1] = MFMA16(a, wN[1][kc], acc[1]);
      }
      // refill wN <- W3 (hidden behind ln2)
#pragma unroll
      for (int nt = 0; nt < 2; ++nt)
#pragma unroll
        for (int kc = 0; kc < 8; ++kc)
          wN[nt][kc] = *(const v8s*)(gwb + 65536 + nt*1024 + kc*8);
#pragma unroll
      for (int nt = 0; nt < 2; ++nt)
#pragma unroll
        for (int r = 0; r < 4; ++r) acc[nt][r] += bia[1][nt];
      ln_silu(acc, 2);

      // ---- layer 3: wN = W3 ----
      acc[0] = fzero; acc[1] = fzero;
#pragma unroll
      for (int kc = 0; kc < 8; ++kc){
        v8s a = *(const v8s*)(pa + kc*32);
        acc[0] = MFMA16(a, wN[0][kc], acc[0]);
        acc[1] = MFMA16(a, wN[1][kc], acc[1]);
      }
      // refill wN <- W2 (for next stage; hidden behind ln3/out/rk4)
#pragma unroll
      for (int nt = 0; nt < 2; ++nt)
#pragma unroll
        for (int kc = 0; kc < 8; ++kc)
          wN[nt][kc] = *(const v8s*)(gwb + nt*1024 + kc*8);
#pragma unroll
      for (int nt = 0; nt < 2; ++nt)
#pragma unroll
        for (int r = 0; r < 4; ++r) acc[nt][r] += bia[2][nt];
      ln_silu(acc, 3);

      // ---- output layer: waves 0,1 (rowbase 0 / 16) ----
      if (wave < 2){
        f32x4 ao = fzero;
        int nn = c15 < 3 ? c15 : 3;
#pragma unroll
        for (int kc = 0; kc < 8; ++kc){
          v8s a = *(const v8s*)(pa + kc*32);
          v8s b = *(const v8s*)(WO + ((kc*4 + q)*4 + nn)*8);
          ao = MFMA16(a, b, ao);
        }
        if (c15 < 3){
#pragma unroll
          for (int r = 0; r < 4; ++r)
            net[(rowbase + q*4 + r)*4 + c15] = ao[r];
        }
      }
      __syncthreads();

      // ---- RK4 + full input-row restore (y, p, 1, 0) ----
      if (tid < 32){
        int s = tid;
        float u = ystg[s*4+0], v = ystg[s*4+1], w = ystg[s*4+2];
        float Om = pL[s*4+0], P1 = pL[s*4+1], ga = pL[s*4+2];
        float kk[3];
        kk[0] = -ga*u                      + gate*(net[s*4+0] + bo0);
        kk[1] = -ga*v - Om*w               + gate*(net[s*4+1] + bo1);
        kk[2] = -2.f*ga*(w + 1.f) + Om*v   + gate*(net[s*4+2] + bo2);
        float ys[3];
#pragma unroll
        for (int c = 0; c < 3; ++c){
          float yc = ycur[s*4+c];
          float k  = kk[c];
          if (stage == 3){
            float accw = ysum[s*4+c] + dt*(1.f/6.f)*k;
            ycur[s*4+c] = accw;
            ys[c] = accw;
            out[(step+1)*(B_*3) + (s0+s)*3 + c] = accw;
          } else {
            float accw = (stage == 0) ? (yc + dt*(1.f/6.f)*k)
                                      : (ysum[s*4+c] + dt*(1.f/3.f)*k);
            ysum[s*4+c] = accw;
            ys[c] = yc + ((stage == 2) ? dt : 0.5f*dt)*k;
          }
          ystg[s*4+c] = ys[c];
        }
        union { u16 h[8]; v8s v; } pk;
        pk.h[0]=f2bf_rne(ys[0]); pk.h[1]=f2bf_rne(ys[1]); pk.h[2]=f2bf_rne(ys[2]);
        pk.h[3]=f2bf_rne(Om);    pk.h[4]=f2bf_rne(P1);    pk.h[5]=f2bf_rne(ga);
        pk.h[6]=0x3F80; pk.h[7]=0;
        *(v8s*)(A + s*AROW) = pk.v;
      }
      __syncthreads();
    }
  }
}

extern "C" void kernel_launch(void* const* d_in, const int* in_sizes, int n_in,
                              void* d_out, int out_size, void* d_ws, size_t ws_size,
                              hipStream_t stream) {
  const float* y0     = (const float*)d_in[0];
  const float* t_span = (const float*)d_in[1];
  const float* params = (const float*)d_in[2];
  const float* W0     = (const float*)d_in[3];
  const float* b0     = (const float*)d_in[4];
  const float* Wh     = (const float*)d_in[5];
  const float* bh     = (const float*)d_in[6];
  const float* ln_g   = (const float*)d_in[7];
  const float* ln_b   = (const float*)d_in[8];
  const float* Wout   = (const float*)d_in[9];
  const float* bout   = (const float*)d_in[10];
  const float* gate   = (const float*)d_in[11];
  float* out = (float*)d_out;
  u16* ws = (u16*)d_ws;

  prep_kernel<<<WS_TOT/256, 256, 0, stream>>>(W0, b0, Wh, Wout, ws);

  hipFuncSetAttribute(reinterpret_cast<const void*>(pinode_kernel),
                      hipFuncAttributeMaxDynamicSharedMemorySize, LDS_TOTAL);
  pinode_kernel<<<NBLOCKS, NTHREADS, LDS_TOTAL, stream>>>(
      y0, t_span, params, bh, ln_g, ln_b, bout, gate, ws, out);
}

// Round 4
// 3288.061 us; speedup vs baseline: 1.1649x; 1.1649x over previous
//
#include <hip/hip_runtime.h>

typedef unsigned short u16;
typedef unsigned int   u32;
typedef short v8s   __attribute__((ext_vector_type(8)));
typedef float f32x4 __attribute__((ext_vector_type(4)));
typedef float f32x2 __attribute__((ext_vector_type(2)));

#define H_ 256
#define B_ 8192
#define NSTEP 31
#define NTHREADS 1024
#define NBLOCKS 256
#define AROW 264   // 256 + 8 pad (u16): 528B row, 16B-aligned, balanced banks for b128

#define MFMA16(a,b,c) __builtin_amdgcn_mfma_f32_16x16x32_bf16(a,b,c,0,0,0)

#define DPP_QP_XOR1 0xB1
#define DPP_QP_XOR2 0x4E
#define DPP_ROR4    0x124
#define DPP_ROR8    0x128

template<int CTRL>
__device__ __forceinline__ float dpp_add(float v){
  return v + __int_as_float(__builtin_amdgcn_update_dpp(0, __float_as_int(v), CTRL, 0xF, 0xF, true));
}
template<int CTRL>
__device__ __forceinline__ float dpp_mov(float v){
  return __int_as_float(__builtin_amdgcn_update_dpp(0, __float_as_int(v), CTRL, 0xF, 0xF, true));
}

__device__ __forceinline__ u16 f2bf_rne(float f){
  unsigned u = __float_as_uint(f);
  u += 0x7fffu + ((u >> 16) & 1u);
  return (u16)(u >> 16);
}
__device__ __forceinline__ u16 f2bf_trunc(float f){
  return (u16)(__float_as_uint(f) >> 16);
}
__device__ __forceinline__ float bf2f(u16 h){
  return __uint_as_float(((u32)h) << 16);
}

// ---- workspace (u16 units) ----
#define WS_W0   0        // [q][n][j] 4*256*8 = 8192 (K-pad to 32; k==6 row = b0)
#define WS_W1   8192     // [n][k]   256*256 = 65536 (Wh[0] transposed)
#define WS_W23  73728    // [l][q][col][kc][j] 2*4*256*64 = 131072
#define WS_TOT  204800

__global__ void prep_kernel(const float* __restrict__ W0,
                            const float* __restrict__ b0,
                            const float* __restrict__ Wh,
                            u16* __restrict__ ws){
  int i = blockIdx.x * 256 + threadIdx.x;
  if (i < 8192){
    int q = i >> 11, n = (i >> 3) & 255, j = i & 7;
    int k = q*8 + j;
    float v = (k < 6) ? W0[k*H_ + n] : ((k == 6) ? b0[n] : 0.f);
    ws[i] = f2bf_rne(v);
  } else if (i < 73728){
    int r = i - 8192;
    int n = r >> 8, k = r & 255;
    ws[i] = f2bf_rne(Wh[k*H_ + n]);
  } else if (i < WS_TOT){
    int r = i - 73728;
    int j = r & 7, kc = (r >> 3) & 7, col = (r >> 6) & 255;
    int q = (r >> 14) & 3, l = (r >> 16) & 1;
    int k = kc*32 + q*8 + j;
    ws[i] = f2bf_rne(Wh[(1 + l)*H_*H_ + k*H_ + col]);
  }
}

// ---- LDS layout (bytes) ----
#define OFF_A      0        // 32*264*2 = 16896
#define OFF_W1     16896    // 256*264*2 = 135168 (pads hold bh bias bf16: [n][256+l])
#define OFF_LNGB   152064   // [4][256] u32 packed (bf16 g | bf16 b<<16) = 4096
#define OFF_PART   156160   // [32 rows][stride 20 f32] = 2560  ((S,Q) f32x2 per cg)
#define OFF_NETP   158720   // [8 cg][32 rows][4] f32 = 4096
#define OFF_DTS    162816   // 128
#define LDS_TOTAL  162944   // <= 163840

__global__ __launch_bounds__(NTHREADS, 1)
void pinode_kernel(const float* __restrict__ y0g, const float* __restrict__ t_span,
                   const float* __restrict__ params, const float* __restrict__ bhg,
                   const float* __restrict__ ln_gg, const float* __restrict__ ln_bg,
                   const float* __restrict__ boutg, const float* __restrict__ gatep,
                   const float* __restrict__ Woutg, const u16* __restrict__ ws,
                   float* __restrict__ out)
{
  extern __shared__ char smem[];
  u16*   A     = (u16*)(smem + OFF_A);
  u16*   W1    = (u16*)(smem + OFF_W1);
  u32*   lngb  = (u32*)(smem + OFF_LNGB);
  float* partf = (float*)(smem + OFF_PART);
  float* netp  = (float*)(smem + OFF_NETP);
  float* dts   = (float*)(smem + OFF_DTS);

  const int tid  = threadIdx.x;
  const int wave = tid >> 6;
  const int lane = tid & 63;
  const int q    = lane >> 4;
  const int c15  = lane & 15;
  const int mg   = wave & 1;          // 16-row group
  const int cg   = wave >> 1;         // 32-col group
  const int colbase = cg * 32;
  const int rowbase = mg * 16;
  const int s0 = blockIdx.x * 32;
  const bool oddl = (c15 & 1);

  // ---- staging ----
  for (int idx = tid; idx < 8192; idx += NTHREADS){
    int n = idx >> 5, ch = idx & 31;
    *(v8s*)(W1 + n*AROW + ch*8) = *(const v8s*)(ws + WS_W1 + n*256 + ch*8);
  }
  if (tid < 768){                       // bh bias -> W1 pad columns
    int l = tid >> 8, n = tid & 255;
    W1[n*AROW + 256 + l] = f2bf_rne(bhg[l*H_ + n]);
  }
  {                                     // ln g/b packed table
    int l = tid >> 8, c = tid & 255;
    lngb[tid] = (u32)f2bf_rne(ln_gg[l*H_ + c]) | ((u32)f2bf_rne(ln_bg[l*H_ + c]) << 16);
  }
  if (tid < NSTEP) dts[tid] = t_span[tid+1] - t_span[tid];

  // ---- RK4 state in wave-0 registers (lanes 0..31) ----
  float yc0=0,yc1=0,yc2=0, ys0=0,ys1=0,ys2=0, su0=0,su1=0,su2=0, Om=0,P1=0,ga=0;
  if (tid < 32){
    int s = tid;
    yc0 = y0g[(s0+s)*3+0]; yc1 = y0g[(s0+s)*3+1]; yc2 = y0g[(s0+s)*3+2];
    Om  = params[(s0+s)*3+0]; P1 = params[(s0+s)*3+1]; ga = params[(s0+s)*3+2];
    ys0 = yc0; ys1 = yc1; ys2 = yc2;
    out[(s0+s)*3+0] = yc0; out[(s0+s)*3+1] = yc1; out[(s0+s)*3+2] = yc2;
    union { u16 h[8]; v8s v; } pk;
    pk.h[0]=f2bf_rne(yc0); pk.h[1]=f2bf_rne(yc1); pk.h[2]=f2bf_rne(yc2);
    pk.h[3]=f2bf_rne(Om);  pk.h[4]=f2bf_rne(P1);  pk.h[5]=f2bf_rne(ga);
    pk.h[6]=0x3F80; pk.h[7]=0;
    *(v8s*)(A + s*AROW) = pk.v;
    v8s z = {0,0,0,0,0,0,0,0};
    *(v8s*)(A + s*AROW + 8)  = z;
    *(v8s*)(A + s*AROW + 16) = z;
    *(v8s*)(A + s*AROW + 24) = z;
  }
  const float gate = gatep[0];
  const float bo0 = boutg[0], bo1 = boutg[1], bo2 = boutg[2];

  // ---- persistent registers ----
  v8s w0f[2];
#pragma unroll
  for (int nt = 0; nt < 2; ++nt)
    w0f[nt] = *(const v8s*)(ws + WS_W0 + (q*256 + colbase + nt*16 + c15)*8);

  float wo[2][3];
#pragma unroll
  for (int nt = 0; nt < 2; ++nt)
#pragma unroll
    for (int o = 0; o < 3; ++o)
      wo[nt][o] = Woutg[(colbase + nt*16 + c15)*3 + o];

  const u16* gwb = ws + WS_W23 + (q*256 + colbase + c15)*64;
  v8s wN[2][8];
#pragma unroll
  for (int nt = 0; nt < 2; ++nt)
#pragma unroll
    for (int kc = 0; kc < 8; ++kc)
      wN[nt][kc] = *(const v8s*)(gwb + nt*1024 + kc*8);   // W2

  const u16* pa = A  + (rowbase + c15)*AROW + q*8;
  const u16* pw = W1 + (colbase + c15)*AROW + q*8;
  const f32x4 fzero = {0.f,0.f,0.f,0.f};
  const int storecol = colbase + c15 + (oddl ? 15 : 0);
  const int bprow = (rowbase + q*4) << 2;

  __syncthreads();

  // LN head: partial sums -> cross-wave -> per-row (rstd, -mu*rstd) in sr/sb
  auto ln_head = [&](f32x4 (&acc)[2], float (&sr)[4], float (&sb)[4]){
    float rs[4], rq[4];
#pragma unroll
    for (int r = 0; r < 4; ++r){
      float a0 = acc[0][r], a1 = acc[1][r];
      rs[r] = a0 + a1;
      rq[r] = a0*a0 + a1*a1;
    }
#pragma unroll
    for (int r = 0; r < 4; ++r){
      float s = rs[r], qq = rq[r];
      s = dpp_add<DPP_QP_XOR1>(s);  qq = dpp_add<DPP_QP_XOR1>(qq);
      s = dpp_add<DPP_QP_XOR2>(s);  qq = dpp_add<DPP_QP_XOR2>(qq);
      s = dpp_add<DPP_ROR4>(s);     qq = dpp_add<DPP_ROR4>(qq);
      s = dpp_add<DPP_ROR8>(s);     qq = dpp_add<DPP_ROR8>(qq);
      rs[r] = s; rq[r] = qq;
    }
    if (c15 < 4){
      float sS = (c15==0) ? rs[0] : (c15==1) ? rs[1] : (c15==2) ? rs[2] : rs[3];
      float sQ = (c15==0) ? rq[0] : (c15==1) ? rq[1] : (c15==2) ? rq[2] : rq[3];
      f32x2 v; v.x = sS; v.y = sQ;
      *(f32x2*)(partf + (rowbase + q*4 + c15)*20 + cg*2) = v;
    }
    __syncthreads();
    int l32 = lane & 31;
    const f32x4* pp = (const f32x4*)(partf + l32*20);
    f32x4 p0 = pp[0], p1 = pp[1], p2 = pp[2], p3 = pp[3];
    float S = ((p0[0]+p0[2])+(p1[0]+p1[2]))+((p2[0]+p2[2])+(p3[0]+p3[2]));
    float Q = ((p0[1]+p0[3])+(p1[1]+p1[3]))+((p2[1]+p2[3])+(p3[1]+p3[3]));
    float mean = S * (1.f/256.f);
    float var  = Q * (1.f/256.f) - mean*mean;
    float rstd = rsqrtf(var + 1e-5f);
    float nmr  = -mean * rstd;
#pragma unroll
    for (int r = 0; r < 4; ++r){
      sr[r] = __int_as_float(__builtin_amdgcn_ds_bpermute(bprow + r*4, __float_as_int(rstd)));
      sb[r] = __int_as_float(__builtin_amdgcn_ds_bpermute(bprow + r*4, __float_as_int(nmr)));
    }
  };

  // LN + SiLU + paired bf16 store (layers 0..2)
  auto ln_mid = [&](f32x4 (&acc)[2], int li){
    float sr[4], sb[4];
    ln_head(acc, sr, sb);
    u32 gb0 = lngb[li*256 + colbase + c15];
    u32 gb1 = lngb[li*256 + colbase + 16 + c15];
    float g0 = __uint_as_float(gb0 << 16), b0_ = __uint_as_float(gb0 & 0xFFFF0000u);
    float g1 = __uint_as_float(gb1 << 16), b1_ = __uint_as_float(gb1 & 0xFFFF0000u);
#pragma unroll
    for (int r = 0; r < 4; ++r){
      float t0 = acc[0][r]*sr[r] + sb[r];
      float t1 = acc[1][r]*sr[r] + sb[r];
      float v0 = t0*g0 + b0_;
      float v1 = t1*g1 + b1_;
      float sv0 = v0 * __builtin_amdgcn_rcpf(1.f + __builtin_amdgcn_exp2f(v0 * -1.44269504f));
      float sv1 = v1 * __builtin_amdgcn_rcpf(1.f + __builtin_amdgcn_exp2f(v1 * -1.44269504f));
      float send = oddl ? sv0 : sv1;
      float recv = dpp_mov<DPP_QP_XOR1>(send);
      float lo = oddl ? recv : sv0;
      float hi = oddl ? sv1 : recv;
      u32 word = (u32)f2bf_trunc(lo) | ((u32)f2bf_trunc(hi) << 16);
      *(u32*)(A + (rowbase + q*4 + r)*AROW + storecol) = word;
    }
    __syncthreads();
  };

  auto bias_add = [&](f32x4 (&acc)[2], int li){
    float bv0 = bf2f(W1[(colbase + c15)*AROW + 256 + (li-1)]);
    float bv1 = bf2f(W1[(colbase + 16 + c15)*AROW + 256 + (li-1)]);
#pragma unroll
    for (int r = 0; r < 4; ++r){ acc[0][r] += bv0; acc[1][r] += bv1; }
  };

#pragma unroll 1
  for (int step = 0; step < NSTEP; ++step){
    float dt = 0.f;
    if (tid < 32) dt = dts[step];
#pragma unroll 1
    for (int stage = 0; stage < 4; ++stage){
      f32x4 acc[2];

      // ---- layer 0 (K=32, bias folded into W0 row 6) ----
      acc[0] = fzero; acc[1] = fzero;
      {
        v8s a = *(const v8s*)(pa);
        acc[0] = MFMA16(a, w0f[0], acc[0]);
        acc[1] = MFMA16(a, w0f[1], acc[1]);
      }
      ln_mid(acc, 0);

      // ---- layer 1: W1 from LDS ----
      acc[0] = fzero; acc[1] = fzero;
#pragma unroll
      for (int kc = 0; kc < 8; ++kc){
        v8s a  = *(const v8s*)(pa + kc*32);
        v8s b0f = *(const v8s*)(pw + kc*32);
        v8s b1f = *(const v8s*)(pw + 16*AROW + kc*32);
        acc[0] = MFMA16(a, b0f, acc[0]);
        acc[1] = MFMA16(a, b1f, acc[1]);
      }
      bias_add(acc, 1);
      ln_mid(acc, 1);

      // ---- layer 2: wN = W2 ----
      acc[0] = fzero; acc[1] = fzero;
#pragma unroll
      for (int kc = 0; kc < 8; ++kc){
        v8s a = *(const v8s*)(pa + kc*32);
        acc[0] = MFMA16(a, wN[0][kc], acc[0]);
        acc[1] = MFMA16(a, wN[1][kc], acc[1]);
      }
#pragma unroll
      for (int nt = 0; nt < 2; ++nt)            // refill wN <- W3 (hidden behind ln2)
#pragma unroll
        for (int kc = 0; kc < 8; ++kc)
          wN[nt][kc] = *(const v8s*)(gwb + 65536 + nt*1024 + kc*8);
      bias_add(acc, 2);
      ln_mid(acc, 2);

      // ---- layer 3: wN = W3 ----
      acc[0] = fzero; acc[1] = fzero;
#pragma unroll
      for (int kc = 0; kc < 8; ++kc){
        v8s a = *(const v8s*)(pa + kc*32);
        acc[0] = MFMA16(a, wN[0][kc], acc[0]);
        acc[1] = MFMA16(a, wN[1][kc], acc[1]);
      }
#pragma unroll
      for (int nt = 0; nt < 2; ++nt)            // refill wN <- W2 (for next stage)
#pragma unroll
        for (int kc = 0; kc < 8; ++kc)
          wN[nt][kc] = *(const v8s*)(gwb + nt*1024 + kc*8);
      bias_add(acc, 3);

      // ---- ln3 + fused fp32 output layer ----
      {
        float sr[4], sb[4];
        ln_head(acc, sr, sb);
        u32 gb0 = lngb[3*256 + colbase + c15];
        u32 gb1 = lngb[3*256 + colbase + 16 + c15];
        float g0 = __uint_as_float(gb0 << 16), b0_ = __uint_as_float(gb0 & 0xFFFF0000u);
        float g1 = __uint_as_float(gb1 << 16), b1_ = __uint_as_float(gb1 & 0xFFFF0000u);
#pragma unroll
        for (int r = 0; r < 4; ++r){
          float t0 = acc[0][r]*sr[r] + sb[r];
          float t1 = acc[1][r]*sr[r] + sb[r];
          float v0 = t0*g0 + b0_;
          float v1 = t1*g1 + b1_;
          float sv0 = v0 * __builtin_amdgcn_rcpf(1.f + __builtin_amdgcn_exp2f(v0 * -1.44269504f));
          float sv1 = v1 * __builtin_amdgcn_rcpf(1.f + __builtin_amdgcn_exp2f(v1 * -1.44269504f));
          float po0 = sv0*wo[0][0] + sv1*wo[1][0];
          float po1 = sv0*wo[0][1] + sv1*wo[1][1];
          float po2 = sv0*wo[0][2] + sv1*wo[1][2];
          po0 = dpp_add<DPP_QP_XOR1>(po0); po1 = dpp_add<DPP_QP_XOR1>(po1); po2 = dpp_add<DPP_QP_XOR1>(po2);
          po0 = dpp_add<DPP_QP_XOR2>(po0); po1 = dpp_add<DPP_QP_XOR2>(po1); po2 = dpp_add<DPP_QP_XOR2>(po2);
          po0 = dpp_add<DPP_ROR4>(po0);    po1 = dpp_add<DPP_ROR4>(po1);    po2 = dpp_add<DPP_ROR4>(po2);
          po0 = dpp_add<DPP_ROR8>(po0);    po1 = dpp_add<DPP_ROR8>(po1);    po2 = dpp_add<DPP_ROR8>(po2);
          if (c15 == 0){
            f32x4 st; st[0] = po0; st[1] = po1; st[2] = po2; st[3] = 0.f;
            *(f32x4*)(netp + (cg*32 + rowbase + q*4 + r)*4) = st;
          }
        }
      }
      __syncthreads();

      // ---- RK4 (wave 0, lanes 0..31; state in registers) ----
      if (tid < 32){
        int s = tid;
        float n0 = 0.f, n1 = 0.f, n2 = 0.f;
#pragma unroll
        for (int c = 0; c < 8; ++c){
          f32x4 v = *(const f32x4*)(netp + (c*32 + s)*4);
          n0 += v[0]; n1 += v[1]; n2 += v[2];
        }
        float k0 = -ga*ys0                         + gate*(n0 + bo0);
        float k1 = -ga*ys1 - Om*ys2                + gate*(n1 + bo1);
        float k2 = -2.f*ga*(ys2 + 1.f) + Om*ys1    + gate*(n2 + bo2);
        if (stage == 0){
          su0 = yc0 + dt*(1.f/6.f)*k0; su1 = yc1 + dt*(1.f/6.f)*k1; su2 = yc2 + dt*(1.f/6.f)*k2;
          ys0 = yc0 + 0.5f*dt*k0; ys1 = yc1 + 0.5f*dt*k1; ys2 = yc2 + 0.5f*dt*k2;
        } else if (stage == 1){
          su0 += dt*(1.f/3.f)*k0; su1 += dt*(1.f/3.f)*k1; su2 += dt*(1.f/3.f)*k2;
          ys0 = yc0 + 0.5f*dt*k0; ys1 = yc1 + 0.5f*dt*k1; ys2 = yc2 + 0.5f*dt*k2;
        } else if (stage == 2){
          su0 += dt*(1.f/3.f)*k0; su1 += dt*(1.f/3.f)*k1; su2 += dt*(1.f/3.f)*k2;
          ys0 = yc0 + dt*k0; ys1 = yc1 + dt*k1; ys2 = yc2 + dt*k2;
        } else {
          yc0 = su0 + dt*(1.f/6.f)*k0; yc1 = su1 + dt*(1.f/6.f)*k1; yc2 = su2 + dt*(1.f/6.f)*k2;
          ys0 = yc0; ys1 = yc1; ys2 = yc2;
          out[(step+1)*(B_*3) + (s0+s)*3 + 0] = yc0;
          out[(step+1)*(B_*3) + (s0+s)*3 + 1] = yc1;
          out[(step+1)*(B_*3) + (s0+s)*3 + 2] = yc2;
        }
        union { u16 h[8]; v8s v; } pk;
        pk.h[0]=f2bf_rne(ys0); pk.h[1]=f2bf_rne(ys1); pk.h[2]=f2bf_rne(ys2);
        pk.h[3]=f2bf_rne(Om);  pk.h[4]=f2bf_rne(P1);  pk.h[5]=f2bf_rne(ga);
        pk.h[6]=0x3F80; pk.h[7]=0;
        *(v8s*)(A + s*AROW) = pk.v;
        v8s z = {0,0,0,0,0,0,0,0};
        *(v8s*)(A + s*AROW + 8)  = z;
        *(v8s*)(A + s*AROW + 16) = z;
        *(v8s*)(A + s*AROW + 24) = z;
      }
      __syncthreads();
    }
  }
}

extern "C" void kernel_launch(void* const* d_in, const int* in_sizes, int n_in,
                              void* d_out, int out_size, void* d_ws, size_t ws_size,
                              hipStream_t stream) {
  const float* y0     = (const float*)d_in[0];
  const float* t_span = (const float*)d_in[1];
  const float* params = (const float*)d_in[2];
  const float* W0     = (const float*)d_in[3];
  const float* b0     = (const float*)d_in[4];
  const float* Wh     = (const float*)d_in[5];
  const float* bh     = (const float*)d_in[6];
  const float* ln_g   = (const float*)d_in[7];
  const float* ln_b   = (const float*)d_in[8];
  const float* Wout   = (const float*)d_in[9];
  const float* bout   = (const float*)d_in[10];
  const float* gate   = (const float*)d_in[11];
  float* out = (float*)d_out;
  u16* ws = (u16*)d_ws;

  prep_kernel<<<WS_TOT/256, 256, 0, stream>>>(W0, b0, Wh, ws);

  hipFuncSetAttribute(reinterpret_cast<const void*>(pinode_kernel),
                      hipFuncAttributeMaxDynamicSharedMemorySize, LDS_TOTAL);
  pinode_kernel<<<NBLOCKS, NTHREADS, LDS_TOTAL, stream>>>(
      y0, t_span, params, bh, ln_g, ln_b, bout, gate, Wout, ws, out);
}

// Round 5
// 1243.618 us; speedup vs baseline: 3.0800x; 2.6439x over previous
//
#include <hip/hip_runtime.h>

typedef unsigned short u16;
typedef unsigned int   u32;
typedef short v8s   __attribute__((ext_vector_type(8)));
typedef float f32x4 __attribute__((ext_vector_type(4)));
typedef float f32x2 __attribute__((ext_vector_type(2)));

#define H_ 256
#define B_ 8192
#define NSTEP 31
#define NTHREADS 512
#define NBLOCKS 256
#define AROW 264   // 256+8 u16 pad: 528B row; 33·16B (odd) -> balanced banks for b128 frags

#define MFMA16(a,b,c) __builtin_amdgcn_mfma_f32_16x16x32_bf16(a,b,c,0,0,0)

#define DPP_QP_XOR1 0xB1
#define DPP_QP_XOR2 0x4E
#define DPP_ROR4    0x124
#define DPP_ROR8    0x128

template<int CTRL>
__device__ __forceinline__ float dpp_add(float v){
  return v + __int_as_float(__builtin_amdgcn_update_dpp(0, __float_as_int(v), CTRL, 0xF, 0xF, true));
}
template<int CTRL>
__device__ __forceinline__ float dpp_mov(float v){
  return __int_as_float(__builtin_amdgcn_update_dpp(0, __float_as_int(v), CTRL, 0xF, 0xF, true));
}

__device__ __forceinline__ u16 f2bf_rne(float f){
  unsigned u = __float_as_uint(f);
  u += 0x7fffu + ((u >> 16) & 1u);
  return (u16)(u >> 16);
}
__device__ __forceinline__ u16 f2bf_trunc(float f){
  return (u16)(__float_as_uint(f) >> 16);
}

// ---- workspace (u16 units) ----
#define WS_W0   0        // [q][n][j] 4*256*8 = 8192 (K-pad to 32; k==6 row = b0)
#define WS_W1   8192     // [n][k]   256*256 = 65536 (Wh[0] transposed)
#define WS_W23  73728    // [l][q][col][kc][j] 2*4*256*64 = 131072 (per-lane contiguous frags)
#define WS_TOT  204800

__global__ void prep_kernel(const float* __restrict__ W0,
                            const float* __restrict__ b0,
                            const float* __restrict__ Wh,
                            u16* __restrict__ ws){
  int i = blockIdx.x * 256 + threadIdx.x;
  if (i < 8192){
    int q = i >> 11, n = (i >> 3) & 255, j = i & 7;
    int k = q*8 + j;
    float v = (k < 6) ? W0[k*H_ + n] : ((k == 6) ? b0[n] : 0.f);
    ws[i] = f2bf_rne(v);
  } else if (i < 73728){
    int r = i - 8192;
    int n = r >> 8, k = r & 255;
    ws[i] = f2bf_rne(Wh[k*H_ + n]);
  } else if (i < WS_TOT){
    int r = i - 73728;
    int j = r & 7, kc = (r >> 3) & 7, col = (r >> 6) & 255;
    int q = (r >> 14) & 3, l = (r >> 16) & 1;
    int k = kc*32 + q*8 + j;
    ws[i] = f2bf_rne(Wh[(1 + l)*H_*H_ + k*H_ + col]);
  }
}

// ---- LDS (bytes) ----
#define PWF 20              // partials row stride in f32
#define OFF_A      0        // 32*264*2 = 16896
#define OFF_W1     16896    // 256*264*2 = 135168
#define OFF_PART   152064   // 32*PWF*4 = 2560
#define OFF_NETP   154624   // 8 cg * 32 rows * 4 f32 = 4096
#define OFF_DTS    158720   // 128
#define LDS_TOTAL  158848

__global__ __launch_bounds__(NTHREADS, 2)
void pinode_kernel(const float* __restrict__ y0g, const float* __restrict__ t_span,
                   const float* __restrict__ params, const float* __restrict__ bhg,
                   const float* __restrict__ ln_gg, const float* __restrict__ ln_bg,
                   const float* __restrict__ boutg, const float* __restrict__ gatep,
                   const float* __restrict__ Woutg, const u16* __restrict__ ws,
                   float* __restrict__ out)
{
  extern __shared__ char smem[];
  u16*   A     = (u16*)(smem + OFF_A);
  u16*   W1    = (u16*)(smem + OFF_W1);
  float* partf = (float*)(smem + OFF_PART);
  float* netp  = (float*)(smem + OFF_NETP);
  float* dts   = (float*)(smem + OFF_DTS);

  const int tid  = threadIdx.x;
  const int wave = tid >> 6;       // = colgroup cg
  const int lane = tid & 63;
  const int q    = lane >> 4;
  const int c15  = lane & 15;
  const int cg   = wave;
  const int colbase = cg * 32;
  const int s0 = blockIdx.x * 32;
  const bool oddl = (c15 & 1);

  // ---- staging ----
  for (int idx = tid; idx < 8192; idx += NTHREADS){
    int n = idx >> 5, ch = idx & 31;
    *(v8s*)(W1 + n*AROW + ch*8) = *(const v8s*)(ws + WS_W1 + n*256 + ch*8);
  }
  if (tid < NSTEP) dts[tid] = t_span[tid+1] - t_span[tid];

  // ---- RK4 state in wave-0 registers (lanes 0..31) ----
  float yc0=0,yc1=0,yc2=0, ys0=0,ys1=0,ys2=0, su0=0,su1=0,su2=0, Om=0,P1=0,ga=0;
  if (tid < 32){
    int s = tid;
    yc0 = y0g[(s0+s)*3+0]; yc1 = y0g[(s0+s)*3+1]; yc2 = y0g[(s0+s)*3+2];
    Om  = params[(s0+s)*3+0]; P1 = params[(s0+s)*3+1]; ga = params[(s0+s)*3+2];
    ys0 = yc0; ys1 = yc1; ys2 = yc2;
    out[(s0+s)*3+0] = yc0; out[(s0+s)*3+1] = yc1; out[(s0+s)*3+2] = yc2;
    union { u16 h[8]; v8s v; } pk;
    pk.h[0]=f2bf_rne(yc0); pk.h[1]=f2bf_rne(yc1); pk.h[2]=f2bf_rne(yc2);
    pk.h[3]=f2bf_rne(Om);  pk.h[4]=f2bf_rne(P1);  pk.h[5]=f2bf_rne(ga);
    pk.h[6]=0x3F80; pk.h[7]=0;
    *(v8s*)(A + s*AROW) = pk.v;
    v8s z = {0,0,0,0,0,0,0,0};   // one-time guard: cols 8..31 finite (stale h later, x0 weights)
    *(v8s*)(A + s*AROW + 8)  = z;
    *(v8s*)(A + s*AROW + 16) = z;
    *(v8s*)(A + s*AROW + 24) = z;
  }
  const float gate = gatep[0];
  const float bo0 = boutg[0], bo1 = boutg[1], bo2 = boutg[2];

  // ---- persistent registers ----
  v8s w0f[2];
#pragma unroll
  for (int nt = 0; nt < 2; ++nt)
    w0f[nt] = *(const v8s*)(ws + WS_W0 + (q*256 + colbase + nt*16 + c15)*8);

  v8s wf[2][8][2];   // W2,W3 fragments (expected to live in AGPRs)
#pragma unroll
  for (int l = 0; l < 2; ++l)
#pragma unroll
    for (int nt = 0; nt < 2; ++nt)
#pragma unroll
      for (int kc = 0; kc < 8; ++kc)
        wf[l][kc][nt] = *(const v8s*)(ws + WS_W23 +
            ((l*4 + q)*256 + colbase + nt*16 + c15)*64 + kc*8);

  float wo[2][3];
#pragma unroll
  for (int nt = 0; nt < 2; ++nt)
#pragma unroll
    for (int o = 0; o < 3; ++o)
      wo[nt][o] = Woutg[(colbase + nt*16 + c15)*3 + o];

  float lng[4][2], lnb[4][2], bia[3][2];
#pragma unroll
  for (int l = 0; l < 4; ++l)
#pragma unroll
    for (int nt = 0; nt < 2; ++nt){
      int col = colbase + nt*16 + c15;
      lng[l][nt] = ln_gg[l*H_ + col];
      lnb[l][nt] = ln_bg[l*H_ + col];
      if (l >= 1) bia[l-1][nt] = bhg[(l-1)*H_ + col];
    }

  const u16* pa = A  + c15*AROW + q*8;           // A-frag base, rows 0..15 (m1: +16*AROW)
  const u16* pw = W1 + (colbase + c15)*AROW + q*8;
  const f32x4 fzero = {0.f,0.f,0.f,0.f};
  const int storecol = colbase + c15 + (oddl ? 15 : 0);

  __syncthreads();

  // LN head: per-row (rstd, -mu*rstd) into sr/sb. One barrier.
  auto ln_head = [&](f32x4 (&acc)[2][2], float (&sr)[2][4], float (&sb)[2][4]){
    float rs[2][4], rq[2][4];
#pragma unroll
    for (int mt = 0; mt < 2; ++mt)
#pragma unroll
      for (int r = 0; r < 4; ++r){
        float a0 = acc[mt][0][r], a1 = acc[mt][1][r];
        rs[mt][r] = a0 + a1;
        rq[mt][r] = a0*a0 + a1*a1;
      }
#pragma unroll
    for (int mt = 0; mt < 2; ++mt)
#pragma unroll
      for (int r = 0; r < 4; ++r){
        float s = rs[mt][r], qq = rq[mt][r];
        s = dpp_add<DPP_QP_XOR1>(s);  qq = dpp_add<DPP_QP_XOR1>(qq);
        s = dpp_add<DPP_QP_XOR2>(s);  qq = dpp_add<DPP_QP_XOR2>(qq);
        s = dpp_add<DPP_ROR4>(s);     qq = dpp_add<DPP_ROR4>(qq);
        s = dpp_add<DPP_ROR8>(s);     qq = dpp_add<DPP_ROR8>(qq);
        rs[mt][r] = s; rq[mt][r] = qq;
      }
    if (c15 < 4){
#pragma unroll
      for (int mt = 0; mt < 2; ++mt){
        float sS = (c15==0) ? rs[mt][0] : (c15==1) ? rs[mt][1] : (c15==2) ? rs[mt][2] : rs[mt][3];
        float sQ = (c15==0) ? rq[mt][0] : (c15==1) ? rq[mt][1] : (c15==2) ? rq[mt][2] : rq[mt][3];
        f32x2 v; v.x = sS; v.y = sQ;
        *(f32x2*)(partf + (mt*16 + q*4 + c15)*PWF + cg*2) = v;
      }
    }
    __syncthreads();
    int l32 = lane & 31;                       // each lane owns one row's stats
    const f32x4* pp = (const f32x4*)(partf + l32*PWF);
    f32x4 p0 = pp[0], p1 = pp[1], p2 = pp[2], p3 = pp[3];
    float S = ((p0[0]+p0[2])+(p1[0]+p1[2]))+((p2[0]+p2[2])+(p3[0]+p3[2]));
    float Q = ((p0[1]+p0[3])+(p1[1]+p1[3]))+((p2[1]+p2[3])+(p3[1]+p3[3]));
    float mean = S * (1.f/256.f);
    float var  = Q * (1.f/256.f) - mean*mean;
    float rstd = rsqrtf(var + 1e-5f);
    float nmr  = -mean * rstd;
#pragma unroll
    for (int mt = 0; mt < 2; ++mt)
#pragma unroll
      for (int r = 0; r < 4; ++r){
        int row = mt*16 + q*4 + r;
        sr[mt][r] = __int_as_float(__builtin_amdgcn_ds_bpermute(row << 2, __float_as_int(rstd)));
        sb[mt][r] = __int_as_float(__builtin_amdgcn_ds_bpermute(row << 2, __float_as_int(nmr)));
      }
  };

  // LN + SiLU + paired b32 store (layers 0..2). Two barriers total.
  auto ln_mid = [&](f32x4 (&acc)[2][2], int li){
    float sr[2][4], sb[2][4];
    ln_head(acc, sr, sb);
    float g0 = lng[li][0], b0_ = lnb[li][0];
    float g1 = lng[li][1], b1_ = lnb[li][1];
#pragma unroll
    for (int mt = 0; mt < 2; ++mt)
#pragma unroll
      for (int r = 0; r < 4; ++r){
        float t0 = acc[mt][0][r]*sr[mt][r] + sb[mt][r];
        float t1 = acc[mt][1][r]*sr[mt][r] + sb[mt][r];
        float v0 = t0*g0 + b0_;
        float v1 = t1*g1 + b1_;
        float sv0 = v0 * __builtin_amdgcn_rcpf(1.f + __builtin_amdgcn_exp2f(v0 * -1.44269504f));
        float sv1 = v1 * __builtin_amdgcn_rcpf(1.f + __builtin_amdgcn_exp2f(v1 * -1.44269504f));
        float send = oddl ? sv0 : sv1;
        float recv = dpp_mov<DPP_QP_XOR1>(send);
        float lo = oddl ? recv : sv0;
        float hi = oddl ? sv1 : recv;
        u32 word = (u32)f2bf_trunc(lo) | ((u32)f2bf_trunc(hi) << 16);
        *(u32*)(A + (mt*16 + q*4 + r)*AROW + storecol) = word;
      }
    __syncthreads();
  };

#pragma unroll 1
  for (int step = 0; step < NSTEP; ++step){
    float dt = 0.f;
    if (tid < 32) dt = dts[step];
#pragma unroll 1
    for (int stage = 0; stage < 4; ++stage){
      f32x4 acc[2][2];

      // ---- layer 0 (K=32; bias row folded; pad rows of W0 are zero) ----
#pragma unroll
      for (int mt = 0; mt < 2; ++mt){ acc[mt][0] = fzero; acc[mt][1] = fzero; }
      {
        v8s a0 = *(const v8s*)(pa);
        v8s a1 = *(const v8s*)(pa + 16*AROW);
        acc[0][0] = MFMA16(a0, w0f[0], acc[0][0]);
        acc[0][1] = MFMA16(a0, w0f[1], acc[0][1]);
        acc[1][0] = MFMA16(a1, w0f[0], acc[1][0]);
        acc[1][1] = MFMA16(a1, w0f[1], acc[1][1]);
      }
      ln_mid(acc, 0);

      // ---- layer 1: W1 from LDS ----
#pragma unroll
      for (int mt = 0; mt < 2; ++mt){ acc[mt][0] = fzero; acc[mt][1] = fzero; }
#pragma unroll
      for (int kc = 0; kc < 8; ++kc){
        v8s a0  = *(const v8s*)(pa + kc*32);
        v8s a1  = *(const v8s*)(pa + 16*AROW + kc*32);
        v8s b0f = *(const v8s*)(pw + kc*32);
        v8s b1f = *(const v8s*)(pw + 16*AROW + kc*32);
        acc[0][0] = MFMA16(a0, b0f, acc[0][0]);
        acc[0][1] = MFMA16(a0, b1f, acc[0][1]);
        acc[1][0] = MFMA16(a1, b0f, acc[1][0]);
        acc[1][1] = MFMA16(a1, b1f, acc[1][1]);
      }
#pragma unroll
      for (int mt = 0; mt < 2; ++mt)
#pragma unroll
        for (int nt = 0; nt < 2; ++nt)
#pragma unroll
          for (int r = 0; r < 4; ++r) acc[mt][nt][r] += bia[0][nt];
      ln_mid(acc, 1);

      // ---- layers 2,3: W from registers ----
#pragma unroll
      for (int l = 0; l < 2; ++l){
#pragma unroll
        for (int mt = 0; mt < 2; ++mt){ acc[mt][0] = fzero; acc[mt][1] = fzero; }
#pragma unroll
        for (int kc = 0; kc < 8; ++kc){
          v8s a0 = *(const v8s*)(pa + kc*32);
          v8s a1 = *(const v8s*)(pa + 16*AROW + kc*32);
          acc[0][0] = MFMA16(a0, wf[l][kc][0], acc[0][0]);
          acc[0][1] = MFMA16(a0, wf[l][kc][1], acc[0][1]);
          acc[1][0] = MFMA16(a1, wf[l][kc][0], acc[1][0]);
          acc[1][1] = MFMA16(a1, wf[l][kc][1], acc[1][1]);
        }
#pragma unroll
        for (int mt = 0; mt < 2; ++mt)
#pragma unroll
          for (int nt = 0; nt < 2; ++nt)
#pragma unroll
            for (int r = 0; r < 4; ++r) acc[mt][nt][r] += bia[1+l][nt];
        if (l == 0) ln_mid(acc, 2);
      }

      // ---- ln3 + fused fp32 output layer (no A-store, no out-MFMA) ----
      {
        float sr[2][4], sb[2][4];
        ln_head(acc, sr, sb);
        float g0 = lng[3][0], b0_ = lnb[3][0];
        float g1 = lng[3][1], b1_ = lnb[3][1];
#pragma unroll
        for (int mt = 0; mt < 2; ++mt)
#pragma unroll
          for (int r = 0; r < 4; ++r){
            float t0 = acc[mt][0][r]*sr[mt][r] + sb[mt][r];
            float t1 = acc[mt][1][r]*sr[mt][r] + sb[mt][r];
            float v0 = t0*g0 + b0_;
            float v1 = t1*g1 + b1_;
            float sv0 = v0 * __builtin_amdgcn_rcpf(1.f + __builtin_amdgcn_exp2f(v0 * -1.44269504f));
            float sv1 = v1 * __builtin_amdgcn_rcpf(1.f + __builtin_amdgcn_exp2f(v1 * -1.44269504f));
            float po0 = sv0*wo[0][0] + sv1*wo[1][0];
            float po1 = sv0*wo[0][1] + sv1*wo[1][1];
            float po2 = sv0*wo[0][2] + sv1*wo[1][2];
            po0 = dpp_add<DPP_QP_XOR1>(po0); po1 = dpp_add<DPP_QP_XOR1>(po1); po2 = dpp_add<DPP_QP_XOR1>(po2);
            po0 = dpp_add<DPP_QP_XOR2>(po0); po1 = dpp_add<DPP_QP_XOR2>(po1); po2 = dpp_add<DPP_QP_XOR2>(po2);
            po0 = dpp_add<DPP_ROR4>(po0);    po1 = dpp_add<DPP_ROR4>(po1);    po2 = dpp_add<DPP_ROR4>(po2);
            po0 = dpp_add<DPP_ROR8>(po0);    po1 = dpp_add<DPP_ROR8>(po1);    po2 = dpp_add<DPP_ROR8>(po2);
            if (c15 == 0){
              f32x4 st; st[0] = po0; st[1] = po1; st[2] = po2; st[3] = 0.f;
              *(f32x4*)(netp + (cg*32 + mt*16 + q*4 + r)*4) = st;
            }
          }
      }
      __syncthreads();

      // ---- RK4 (wave 0; state in registers) + A input-row rewrite ----
      if (tid < 32){
        int s = tid;
        float n0 = 0.f, n1 = 0.f, n2 = 0.f;
#pragma unroll
        for (int c = 0; c < 8; ++c){
          f32x4 v = *(const f32x4*)(netp + (c*32 + s)*4);
          n0 += v[0]; n1 += v[1]; n2 += v[2];
        }
        float k0 = -ga*ys0                      + gate*(n0 + bo0);
        float k1 = -ga*ys1 - Om*ys2             + gate*(n1 + bo1);
        float k2 = -2.f*ga*(ys2 + 1.f) + Om*ys1 + gate*(n2 + bo2);
        if (stage == 0){
          su0 = yc0 + dt*(1.f/6.f)*k0; su1 = yc1 + dt*(1.f/6.f)*k1; su2 = yc2 + dt*(1.f/6.f)*k2;
          ys0 = yc0 + 0.5f*dt*k0; ys1 = yc1 + 0.5f*dt*k1; ys2 = yc2 + 0.5f*dt*k2;
        } else if (stage == 1){
          su0 += dt*(1.f/3.f)*k0; su1 += dt*(1.f/3.f)*k1; su2 += dt*(1.f/3.f)*k2;
          ys0 = yc0 + 0.5f*dt*k0; ys1 = yc1 + 0.5f*dt*k1; ys2 = yc2 + 0.5f*dt*k2;
        } else if (stage == 2){
          su0 += dt*(1.f/3.f)*k0; su1 += dt*(1.f/3.f)*k1; su2 += dt*(1.f/3.f)*k2;
          ys0 = yc0 + dt*k0; ys1 = yc1 + dt*k1; ys2 = yc2 + dt*k2;
        } else {
          yc0 = su0 + dt*(1.f/6.f)*k0; yc1 = su1 + dt*(1.f/6.f)*k1; yc2 = su2 + dt*(1.f/6.f)*k2;
          ys0 = yc0; ys1 = yc1; ys2 = yc2;
          out[(step+1)*(B_*3) + (s0+s)*3 + 0] = yc0;
          out[(step+1)*(B_*3) + (s0+s)*3 + 1] = yc1;
          out[(step+1)*(B_*3) + (s0+s)*3 + 2] = yc2;
        }
        union { u16 h[8]; v8s v; } pk;
        pk.h[0]=f2bf_rne(ys0); pk.h[1]=f2bf_rne(ys1); pk.h[2]=f2bf_rne(ys2);
        pk.h[3]=f2bf_rne(Om);  pk.h[4]=f2bf_rne(P1);  pk.h[5]=f2bf_rne(ga);
        pk.h[6]=0x3F80; pk.h[7]=0;
        *(v8s*)(A + s*AROW) = pk.v;
      }
      __syncthreads();
    }
  }
}

extern "C" void kernel_launch(void* const* d_in, const int* in_sizes, int n_in,
                              void* d_out, int out_size, void* d_ws, size_t ws_size,
                              hipStream_t stream) {
  const float* y0     = (const float*)d_in[0];
  const float* t_span = (const float*)d_in[1];
  const float* params = (const float*)d_in[2];
  const float* W0     = (const float*)d_in[3];
  const float* b0     = (const float*)d_in[4];
  const float* Wh     = (const float*)d_in[5];
  const float* bh     = (const float*)d_in[6];
  const float* ln_g   = (const float*)d_in[7];
  const float* ln_b   = (const float*)d_in[8];
  const float* Wout   = (const float*)d_in[9];
  const float* bout   = (const float*)d_in[10];
  const float* gate   = (const float*)d_in[11];
  float* out = (float*)d_out;
  u16* ws = (u16*)d_ws;

  prep_kernel<<<WS_TOT/256, 256, 0, stream>>>(W0, b0, Wh, ws);

  hipFuncSetAttribute(reinterpret_cast<const void*>(pinode_kernel),
                      hipFuncAttributeMaxDynamicSharedMemorySize, LDS_TOTAL);
  pinode_kernel<<<NBLOCKS, NTHREADS, LDS_TOTAL, stream>>>(
      y0, t_span, params, bh, ln_g, ln_b, bout, gate, Wout, ws, out);
}